// Round 1
// baseline (1217.812 us; speedup 1.0000x reference)
//
#include <hip/hip_runtime.h>
#include <math.h>

#define NF 39
#define ND 13
#define NS 26                         // sparse fields
#define KDIM 16
#define FEAT 260013
#define NPAIRS (NF * (NF + 1) / 2)    // 780 unordered pairs (i<=j)

// ---- transposed-layout path ----
#define ROWF4 4                       // float4 per (row,feature) vector (16 floats)
#define CHUNKF4 (NF * ROWF4)          // 156 float4 per feature chunk in WT
#define CHUNKF4_PAD 157               // bank-spread pad for LDS chunk copies
#define PAIR_SLOTS 832                // 13 passes * 64 pair slots (4 lanes/pair)
#define CPASSES 13
#define TFEAT 26                      // features per transpose block
#define TROWF4 (TFEAT * ROWF4)        // 104
#define TROWF4_PAD 105                // bank-spread pad

// WT[f][i][k] = W[i][f][k]. Read 39 contiguous 1664B row-slices, write one
// contiguous 63.4KB block. LDS 65,520B -> 2 blocks/CU.
__global__ __launch_bounds__(256) void ffm_transpose(
    const float4* __restrict__ W4,   // [39 * FEAT * 4] f4
    float4* __restrict__ WT4)        // [FEAT * 156] f4
{
    __shared__ float4 sT[NF * TROWF4_PAD];   // 39*105 f4 = 65,520 B
    const int fbase = blockIdx.x * TFEAT;
    const int tid   = threadIdx.x;

    #pragma unroll 8
    for (int r = tid; r < NF * TROWF4; r += 256) {
        int row = r / TROWF4;
        int w   = r - row * TROWF4;          // feature-local*4 + k4
        if (fbase + (w >> 2) < FEAT)
            sT[row * TROWF4_PAD + w] = W4[((size_t)row * FEAT + fbase) * 4 + w];
    }
    __syncthreads();

    #pragma unroll 8
    for (int o = tid; o < TFEAT * CHUNKF4; o += 256) {
        int fl  = o / CHUNKF4;
        int rem = o - fl * CHUNKF4;          // i*4 + k4
        int i   = rem >> 2;
        int k4  = rem & 3;
        int f   = fbase + fl;
        if (f < FEAT)
            WT4[(size_t)f * CHUNKF4 + rem] = sT[i * TROWF4_PAD + (fl << 2) + k4];
    }
}

// One block per sample. Stage the 26 sparse feature-chunks (26*2496B) from WT
// into LDS as contiguous streams; dense chunks (13, sample-invariant, 32KB
// total chip-wide) are read direct and stay L2-hot. Pairs: 4 lanes/pair, each
// lane loads both float4 fragments and accumulates w * partial-dot; the block
// reduction sums partials -> no per-pair cross-lane shuffles at all.
__global__ __launch_bounds__(256) void ffm_main(
    const float* __restrict__ x,       // [B, 39]
    const float4* __restrict__ WT4,    // [FEAT * 156] f4
    const float* __restrict__ fc_w,    // [FEAT]
    const float* __restrict__ bias,    // [1]
    const int*   __restrict__ offsets, // [39]
    float* __restrict__ out,           // [B]
    int B)
{
    __shared__ float4         sC[NS * CHUNKF4_PAD];  // 65,312 B
    __shared__ int            sgb[NF];               // f*156 (f4 base in WT)
    __shared__ int            sfeat[NF];
    __shared__ float          sxm[NF];
    __shared__ unsigned short spij[PAIR_SLOTS];
    __shared__ float          sw[PAIR_SLOTS];
    __shared__ float          sred[4];

    const int b   = blockIdx.x;
    const int tid = threadIdx.x;

    if (tid < NF) {
        float xv   = x[(size_t)b * NF + tid];
        int idx    = (tid < ND) ? 0 : (int)floorf(xv);
        int f      = idx + offsets[tid];
        sfeat[tid] = f;
        sgb[tid]   = f * CHUNKF4;
        sxm[tid]   = (tid < ND) ? xv : 1.0f;
    }
    __syncthreads();

    float acc = 0.0f;
    if (tid < NF) acc += fc_w[sfeat[tid]];   // linear term

    // pair table: (i,j) + weight. Mask algebra (row i<38 kept, all j):
    //   i==j<38: xm^2 ; i<j<38: 2*xm_i*xm_j ; i<j==38: xm_i*xm_j ; (38,38): 0
    for (int p = tid; p < PAIR_SLOTS; p += 256) {
        int i = 0, j = 0; float w = 0.0f;
        if (p < NPAIRS) {
            int base = 0, ii = 0;
            while (p >= base + (NF - ii)) { base += NF - ii; ++ii; }
            i = ii; j = ii + (p - base);
            if (i == j)          w = (i < NF - 1) ? sxm[i] * sxm[i] : 0.0f;
            else if (j < NF - 1) w = 2.0f * sxm[i] * sxm[j];
            else                 w = sxm[i] * sxm[j];
        }
        spij[p] = (unsigned short)(i | (j << 8));
        sw[p]   = w;
    }

    // stage 26 sparse chunks: contiguous 2496B streams from WT
    #pragma unroll 8
    for (int t = tid; t < NS * CHUNKF4; t += 256) {
        int c = t / CHUNKF4;
        int w = t - c * CHUNKF4;
        sC[c * CHUNKF4_PAD + w] = WT4[(size_t)sgb[ND + c] + w];
    }
    __syncthreads();

    const int slot = tid >> 2;   // 0..63 : pair slot within pass
    const int q    = tid & 3;    // float4 index within vector

    #pragma unroll 4
    for (int pass = 0; pass < CPASSES; ++pass) {
        int   p   = pass * 64 + slot;
        int   ij  = spij[p];
        int   i   = ij & 0xff;
        int   j   = ij >> 8;
        float wgt = sw[p];

        // vij = W[i][f_j] fragment, vji = W[j][f_i] fragment
        float4 a = (j >= ND) ? sC[(j - ND) * CHUNKF4_PAD + (i << 2) + q]
                             : WT4[(size_t)sgb[j] + (i << 2) + q];
        float4 v = (i >= ND) ? sC[(i - ND) * CHUNKF4_PAD + (j << 2) + q]
                             : WT4[(size_t)sgb[i] + (j << 2) + q];

        acc += wgt * (a.x * v.x + a.y * v.y + a.z * v.z + a.w * v.w);
    }

    // block reduction: wave64 shuffle, then LDS across 4 waves
    #pragma unroll
    for (int off = 32; off > 0; off >>= 1)
        acc += __shfl_down(acc, off, 64);
    if ((tid & 63) == 0) sred[tid >> 6] = acc;
    __syncthreads();

    if (tid == 0) {
        float z = sred[0] + sred[1] + sred[2] + sred[3] + bias[0];
        out[b] = 1.0f / (1.0f + expf(-z));
    }
}

// ---- fallback: previous verified kernel (native W layout, 8 lanes/pair) ----
#define PASSES ((NPAIRS + 31) / 32)
__global__ __launch_bounds__(256) void ffm_kernel(
    const float* __restrict__ x, const float* __restrict__ W,
    const float* __restrict__ fc_w, const float* __restrict__ bias,
    const int* __restrict__ offsets, float* __restrict__ out, int B)
{
    __shared__ int            sf[NF];
    __shared__ float          sxm[NF];
    __shared__ unsigned short spij[NPAIRS];
    __shared__ float          sred[4];

    const int b   = blockIdx.x;
    const int tid = threadIdx.x;

    if (tid < NF) {
        float xv = x[(size_t)b * NF + tid];
        int idx  = (tid < ND) ? 0 : (int)floorf(xv);
        sf[tid]  = idx + offsets[tid];
        sxm[tid] = (tid < ND) ? xv : 1.0f;
    }
    for (int p = tid; p < NPAIRS; p += 256) {
        int i = 0, base = 0;
        while (p >= base + (NF - i)) { base += NF - i; ++i; }
        int j = i + (p - base);
        spij[p] = (unsigned short)(i | (j << 8));
    }
    __syncthreads();

    const int slot = tid >> 3;
    const int quad = (tid >> 2) & 1;
    const int qi   = tid & 3;

    float acc = 0.0f;
    if (tid < NF) acc += fc_w[sf[tid]];

    #pragma unroll 5
    for (int pass = 0; pass < PASSES; ++pass) {
        int p  = pass * 32 + slot;
        int pc = (p < NPAIRS) ? p : (NPAIRS - 1);
        int ij = spij[pc];
        int i  = ij & 0xff;
        int j  = ij >> 8;

        float w;
        if (i == j)          w = (i < NF - 1) ? sxm[i] * sxm[i] : 0.0f;
        else if (j < NF - 1) w = 2.0f * sxm[i] * sxm[j];
        else                 w = sxm[i] * sxm[j];
        if (p >= NPAIRS) w = 0.0f;

        int row  = quad ? j : i;
        int feat = quad ? sf[i] : sf[j];
        const float4* vp = (const float4*)(W + ((size_t)row * FEAT + feat) * KDIM);
        float4 v = vp[qi];

        float4 u;
        u.x = __shfl_xor(v.x, 4, 64);
        u.y = __shfl_xor(v.y, 4, 64);
        u.z = __shfl_xor(v.z, 4, 64);
        u.w = __shfl_xor(v.w, 4, 64);

        float d = v.x * u.x + v.y * u.y + v.z * u.z + v.w * u.w;
        acc += 0.5f * w * d;
    }

    #pragma unroll
    for (int off = 32; off > 0; off >>= 1)
        acc += __shfl_down(acc, off, 64);
    if ((tid & 63) == 0) sred[tid >> 6] = acc;
    __syncthreads();

    if (tid == 0) {
        float z = sred[0] + sred[1] + sred[2] + sred[3] + bias[0];
        out[b] = 1.0f / (1.0f + expf(-z));
    }
}

extern "C" void kernel_launch(void* const* d_in, const int* in_sizes, int n_in,
                              void* d_out, int out_size, void* d_ws, size_t ws_size,
                              hipStream_t stream) {
    const float* x       = (const float*)d_in[0];
    const float* W       = (const float*)d_in[1];
    const float* fc_w    = (const float*)d_in[2];
    const float* bias    = (const float*)d_in[3];
    const int*   offsets = (const int*)d_in[4];

    float* out = (float*)d_out;
    const int B = in_sizes[0] / NF;

    const size_t WT_BYTES = (size_t)FEAT * NF * KDIM * sizeof(float); // ~649 MB

    if (d_ws != nullptr && ws_size >= WT_BYTES) {
        float4* WT4 = (float4*)d_ws;
        const int tgrid = (FEAT + TFEAT - 1) / TFEAT;   // 10,001
        ffm_transpose<<<tgrid, 256, 0, stream>>>((const float4*)W, WT4);
        ffm_main<<<B, 256, 0, stream>>>(x, (const float4*)WT4, fc_w, bias,
                                        offsets, out, B);
    } else {
        ffm_kernel<<<B, 256, 0, stream>>>(x, W, fc_w, bias, offsets, out, B);
    }
}

// Round 2
// 1001.354 us; speedup vs baseline: 1.2162x; 1.2162x over previous
//
#include <hip/hip_runtime.h>
#include <math.h>

#define NF 39
#define ND 13
#define NS 26                         // sparse fields
#define KDIM 16
#define FEAT 260013
#define NPAIRS (NF * (NF + 1) / 2)    // 780 unordered pairs (i<=j)

// ---- transposed-layout path ----
#define ROWF4 4                       // float4 per (row,feature) vector (16 floats)
#define CHUNKF4 (NF * ROWF4)          // 156 float4 per feature chunk in WT
#define PAIR_SLOTS 832                // 13 passes * 64 pair slots (4 lanes/pair)
#define CPASSES 13
#define TFEAT 20                      // features per transpose block
#define TROWF4 (TFEAT * ROWF4)        // 80 f4 per row-slice
#define TROWF4_PAD 81                 // bank-spread pad
#define TTHREADS 512

// WT[f][i][k] = W[i][f][k]. Per block: read 39 contiguous 1280B row-slices,
// write 20 contiguous 2496B chunks (one 49.9KB contiguous output region).
// LDS 50,544B -> 3 blocks/CU; 512 thr -> 24 waves/CU (75% occupancy).
__global__ __launch_bounds__(TTHREADS) void ffm_transpose(
    const float4* __restrict__ W4,   // [39 * FEAT * 4] f4
    float4* __restrict__ WT4)        // [FEAT * 156] f4
{
    __shared__ float4 sT[NF * TROWF4_PAD];   // 39*81 f4 = 50,544 B
    const int fbase  = blockIdx.x * TFEAT;
    const int fbase4 = fbase * 4;
    const int tid    = threadIdx.x;

    #pragma unroll
    for (int r = tid; r < NF * TROWF4; r += TTHREADS) {
        int row = r / TROWF4;
        int w   = r - row * TROWF4;          // feature-local*4 + k4
        if (fbase + (w >> 2) < FEAT)
            sT[row * TROWF4_PAD + w] = W4[(size_t)row * (FEAT * 4) + fbase4 + w];
    }
    __syncthreads();

    #pragma unroll
    for (int o = tid; o < TFEAT * CHUNKF4; o += TTHREADS) {
        int fl  = o / CHUNKF4;               // feature-local
        int rem = o - fl * CHUNKF4;          // i*4 + k4
        int f   = fbase + fl;
        if (f < FEAT)
            WT4[(size_t)f * CHUNKF4 + rem] =
                sT[(rem >> 2) * TROWF4_PAD + (fl << 2) + (rem & 3)];
    }
}

// One block per sample, 4 lanes per pair, direct loads from WT (no staging:
// each chunk element is consumed exactly once per sample, so LDS staging has
// zero reuse -- rely on 128B-line locality inside the contiguous 2.5KB chunks
// instead). LDS ~5.6KB -> 8 blocks/CU, full thread occupancy.
__global__ __launch_bounds__(256) void ffm_main(
    const float* __restrict__ x,       // [B, 39]
    const float4* __restrict__ WT4,    // [FEAT * 156] f4
    const float* __restrict__ fc_w,    // [FEAT]
    const float* __restrict__ bias,    // [1]
    const int*   __restrict__ offsets, // [39]
    float* __restrict__ out,           // [B]
    int B)
{
    __shared__ int            sgb[NF];       // f * 156 (f4 base of chunk in WT)
    __shared__ int            sfeat[NF];
    __shared__ float          sxm[NF];
    __shared__ unsigned short spij[PAIR_SLOTS];
    __shared__ float          sw[PAIR_SLOTS];
    __shared__ float          sred[4];

    const int b   = blockIdx.x;
    const int tid = threadIdx.x;

    if (tid < NF) {
        float xv   = x[(size_t)b * NF + tid];
        int idx    = (tid < ND) ? 0 : (int)floorf(xv);
        int f      = idx + offsets[tid];
        sfeat[tid] = f;
        sgb[tid]   = f * CHUNKF4;
        sxm[tid]   = (tid < ND) ? xv : 1.0f;
    }
    __syncthreads();

    float acc = 0.0f;
    if (tid < NF) acc += fc_w[sfeat[tid]];   // linear term

    // pair table: (i,j) + weight. Mask algebra (row i<38 kept, all j):
    //   i==j<38: xm^2 ; i<j<38: 2*xm_i*xm_j ; i<j==38: xm_i*xm_j ; (38,38): 0
    for (int p = tid; p < PAIR_SLOTS; p += 256) {
        int i = 0, j = 0; float w = 0.0f;
        if (p < NPAIRS) {
            int base = 0, ii = 0;
            while (p >= base + (NF - ii)) { base += NF - ii; ++ii; }
            i = ii; j = ii + (p - base);
            if (i == j)          w = (i < NF - 1) ? sxm[i] * sxm[i] : 0.0f;
            else if (j < NF - 1) w = 2.0f * sxm[i] * sxm[j];
            else                 w = sxm[i] * sxm[j];
        }
        spij[p] = (unsigned short)(i | (j << 8));
        sw[p]   = w;
    }
    __syncthreads();

    const int slot = tid >> 2;   // 0..63 : pair slot within pass
    const int q    = tid & 3;    // float4 index within vector

    #pragma unroll 4
    for (int pass = 0; pass < CPASSES; ++pass) {
        int   p   = pass * 64 + slot;
        int   ij  = spij[p];
        int   i   = ij & 0xff;
        int   j   = ij >> 8;
        float wgt = sw[p];

        // a = W[i][f_j] fragment (scattered 64B within chunk f_j)
        // v = W[j][f_i] fragment (contiguous along j within chunk f_i)
        float4 a = WT4[(size_t)sgb[j] + (i << 2) + q];
        float4 v = WT4[(size_t)sgb[i] + (j << 2) + q];

        acc += wgt * (a.x * v.x + a.y * v.y + a.z * v.z + a.w * v.w);
    }

    // block reduction: wave64 shuffle, then LDS across 4 waves
    #pragma unroll
    for (int off = 32; off > 0; off >>= 1)
        acc += __shfl_down(acc, off, 64);
    if ((tid & 63) == 0) sred[tid >> 6] = acc;
    __syncthreads();

    if (tid == 0) {
        float z = sred[0] + sred[1] + sred[2] + sred[3] + bias[0];
        out[b] = 1.0f / (1.0f + expf(-z));
    }
}

// ---- fallback: verified round-0 kernel (native W layout, 8 lanes/pair) ----
#define PASSES ((NPAIRS + 31) / 32)
__global__ __launch_bounds__(256) void ffm_kernel(
    const float* __restrict__ x, const float* __restrict__ W,
    const float* __restrict__ fc_w, const float* __restrict__ bias,
    const int* __restrict__ offsets, float* __restrict__ out, int B)
{
    __shared__ int            sf[NF];
    __shared__ float          sxm[NF];
    __shared__ unsigned short spij[NPAIRS];
    __shared__ float          sred[4];

    const int b   = blockIdx.x;
    const int tid = threadIdx.x;

    if (tid < NF) {
        float xv = x[(size_t)b * NF + tid];
        int idx  = (tid < ND) ? 0 : (int)floorf(xv);
        sf[tid]  = idx + offsets[tid];
        sxm[tid] = (tid < ND) ? xv : 1.0f;
    }
    for (int p = tid; p < NPAIRS; p += 256) {
        int i = 0, base = 0;
        while (p >= base + (NF - i)) { base += NF - i; ++i; }
        int j = i + (p - base);
        spij[p] = (unsigned short)(i | (j << 8));
    }
    __syncthreads();

    const int slot = tid >> 3;
    const int quad = (tid >> 2) & 1;
    const int qi   = tid & 3;

    float acc = 0.0f;
    if (tid < NF) acc += fc_w[sf[tid]];

    #pragma unroll 5
    for (int pass = 0; pass < PASSES; ++pass) {
        int p  = pass * 32 + slot;
        int pc = (p < NPAIRS) ? p : (NPAIRS - 1);
        int ij = spij[pc];
        int i  = ij & 0xff;
        int j  = ij >> 8;

        float w;
        if (i == j)          w = (i < NF - 1) ? sxm[i] * sxm[i] : 0.0f;
        else if (j < NF - 1) w = 2.0f * sxm[i] * sxm[j];
        else                 w = sxm[i] * sxm[j];
        if (p >= NPAIRS) w = 0.0f;

        int row  = quad ? j : i;
        int feat = quad ? sf[i] : sf[j];
        const float4* vp = (const float4*)(W + ((size_t)row * FEAT + feat) * KDIM);
        float4 v = vp[qi];

        float4 u;
        u.x = __shfl_xor(v.x, 4, 64);
        u.y = __shfl_xor(v.y, 4, 64);
        u.z = __shfl_xor(v.z, 4, 64);
        u.w = __shfl_xor(v.w, 4, 64);

        float d = v.x * u.x + v.y * u.y + v.z * u.z + v.w * u.w;
        acc += 0.5f * w * d;
    }

    #pragma unroll
    for (int off = 32; off > 0; off >>= 1)
        acc += __shfl_down(acc, off, 64);
    if ((tid & 63) == 0) sred[tid >> 6] = acc;
    __syncthreads();

    if (tid == 0) {
        float z = sred[0] + sred[1] + sred[2] + sred[3] + bias[0];
        out[b] = 1.0f / (1.0f + expf(-z));
    }
}

extern "C" void kernel_launch(void* const* d_in, const int* in_sizes, int n_in,
                              void* d_out, int out_size, void* d_ws, size_t ws_size,
                              hipStream_t stream) {
    const float* x       = (const float*)d_in[0];
    const float* W       = (const float*)d_in[1];
    const float* fc_w    = (const float*)d_in[2];
    const float* bias    = (const float*)d_in[3];
    const int*   offsets = (const int*)d_in[4];

    float* out = (float*)d_out;
    const int B = in_sizes[0] / NF;

    const size_t WT_BYTES = (size_t)FEAT * NF * KDIM * sizeof(float); // ~649 MB

    if (d_ws != nullptr && ws_size >= WT_BYTES) {
        float4* WT4 = (float4*)d_ws;
        const int tgrid = (FEAT + TFEAT - 1) / TFEAT;   // 13,001
        ffm_transpose<<<tgrid, TTHREADS, 0, stream>>>((const float4*)W, WT4);
        ffm_main<<<B, 256, 0, stream>>>(x, (const float4*)WT4, fc_w, bias,
                                        offsets, out, B);
    } else {
        ffm_kernel<<<B, 256, 0, stream>>>(x, W, fc_w, bias, offsets, out, B);
    }
}

// Round 3
// 989.918 us; speedup vs baseline: 1.2302x; 1.0116x over previous
//
#include <hip/hip_runtime.h>
#include <math.h>

#define NF 39
#define ND 13
#define NS 26                         // sparse fields
#define KDIM 16
#define FEAT 260013
#define NPAIRS (NF * (NF + 1) / 2)    // 780 unordered pairs (i<=j)

// ---- transposed-layout path ----
#define ROWF4 4                       // float4 per (row,feature) vector
#define CHUNKF4 (NF * ROWF4)          // 156 f4 per feature chunk in WT
#define CHUNKF4_PAD 157               // stride 157 f4 == 20 mod 32 banks: 2-way max
#define PAIR_SLOTS 832                // 13 passes * 64 pair slots (4 lanes/pair)
#define CPASSES 13
#define TFEAT 20                      // features per transpose block
#define TROWF4 (TFEAT * ROWF4)        // 80
#define TROWF4_PAD 81
#define TTHREADS 512
#define BITWORDS ((FEAT + 31) / 32)   // 8126 u32 used-feature bitmap
#define MAIN_BLOCKS 512               // 2 blocks/CU

__global__ __launch_bounds__(256) void ffm_clear_bits(unsigned* __restrict__ bits)
{
    int t = blockIdx.x * 256 + threadIdx.x;
    if (t < BITWORDS) bits[t] = 0u;
}

// mark features referenced by the batch (sparse fields only; dense f<13 implicit)
__global__ __launch_bounds__(256) void ffm_mark_bits(
    const float* __restrict__ x, const int* __restrict__ offsets,
    unsigned* __restrict__ bits, int B)
{
    int t = blockIdx.x * 256 + threadIdx.x;
    if (t >= B * NS) return;
    int b  = t / NS;
    int jj = ND + (t - b * NS);
    int f  = offsets[jj] + (int)floorf(x[(size_t)b * NF + jj]);
    atomicOr(&bits[f >> 5], 1u << (f & 31));
}

// WT[f][i][k] = W[i][f][k], written ONLY for used features (~1/3 of table).
// Read: 39 contiguous 1280B row-slices (full stream). Write: used 2496B chunks.
__global__ __launch_bounds__(TTHREADS) void ffm_transpose(
    const float4* __restrict__ W4,    // [39 * FEAT * 4] f4
    float4* __restrict__ WT4,         // [FEAT * 156] f4
    const unsigned* __restrict__ bits)
{
    __shared__ float4 sT[NF * TROWF4_PAD];   // 50,544 B -> 3 blocks/CU
    __shared__ char   sUsed[TFEAT];
    const int fbase  = blockIdx.x * TFEAT;
    const int fbase4 = fbase * 4;
    const int tid    = threadIdx.x;

    if (tid < TFEAT) {
        int f = fbase + tid;
        int u = 0;
        if (f < FEAT)
            u = (f < ND) ? 1 : (int)((bits[f >> 5] >> (f & 31)) & 1u);
        sUsed[tid] = (char)u;
    }

    #pragma unroll
    for (int r = tid; r < NF * TROWF4; r += TTHREADS) {
        int row = r / TROWF4;
        int w   = r - row * TROWF4;
        if (fbase + (w >> 2) < FEAT)
            sT[row * TROWF4_PAD + w] = W4[(size_t)row * (FEAT * 4) + fbase4 + w];
    }
    __syncthreads();

    #pragma unroll
    for (int o = tid; o < TFEAT * CHUNKF4; o += TTHREADS) {
        int fl  = o / CHUNKF4;
        int rem = o - fl * CHUNKF4;
        int f   = fbase + fl;
        if (f < FEAT && sUsed[fl])
            WT4[(size_t)f * CHUNKF4 + rem] =
                sT[(rem >> 2) * TROWF4_PAD + (fl << 2) + (rem & 3)];
    }
}

// Persistent blocks: 512 blocks x 8 samples. Per sample: stage the 26 sparse
// chunks coalesced into LDS (each chunk read from HBM exactly once, as a
// contiguous 2.5KB stream), then all pair-dots from LDS. Dense chunks (32KB,
// sample-invariant) read direct (L2-hot). Two resident blocks/CU alternate
// stage/compute phases to hide latency.
__global__ __launch_bounds__(256) void ffm_main(
    const float* __restrict__ x,       // [B, 39]
    const float4* __restrict__ WT4,    // [FEAT * 156] f4
    const float* __restrict__ fc_w,    // [FEAT]
    const float* __restrict__ bias,    // [1]
    const int*   __restrict__ offsets, // [39]
    float* __restrict__ out,           // [B]
    int B)
{
    __shared__ float4         sC[NS * CHUNKF4_PAD];  // 65,312 B
    __shared__ int            sgb[NF];
    __shared__ int            sfeat[NF];
    __shared__ float          sxm[NF];
    __shared__ unsigned short spij[PAIR_SLOTS];
    __shared__ float          sw[PAIR_SLOTS];
    __shared__ float          sred[4];

    const int tid  = threadIdx.x;
    const int slot = tid >> 2;   // 0..63
    const int q    = tid & 3;

    // static pair table (i,j), built once
    for (int p = tid; p < PAIR_SLOTS; p += 256) {
        int i = 0, j = 0;
        if (p < NPAIRS) {
            int base = 0, ii = 0;
            while (p >= base + (NF - ii)) { base += NF - ii; ++ii; }
            i = ii; j = ii + (p - base);
        }
        spij[p] = (unsigned short)(i | (j << 8));
    }

    for (int b = blockIdx.x; b < B; b += MAIN_BLOCKS) {
        __syncthreads();   // protect sC/sxm from previous sample's readers
        if (tid < NF) {
            float xv   = x[(size_t)b * NF + tid];
            int idx    = (tid < ND) ? 0 : (int)floorf(xv);
            int f      = idx + offsets[tid];
            sfeat[tid] = f;
            sgb[tid]   = f * CHUNKF4;
            sxm[tid]   = (tid < ND) ? xv : 1.0f;
        }
        __syncthreads();

        // per-sample pair weights. Mask algebra (row i<38 kept, all j):
        //   i==j<38: xm^2 ; i<j<38: 2*xm_i*xm_j ; i<j==38: xm_i*xm_j ; (38,38): 0
        for (int p = tid; p < PAIR_SLOTS; p += 256) {
            float w = 0.0f;
            if (p < NPAIRS) {
                int ij = spij[p];
                int i  = ij & 0xff;
                int j  = ij >> 8;
                if (i == j)          w = (i < NF - 1) ? sxm[i] * sxm[i] : 0.0f;
                else if (j < NF - 1) w = 2.0f * sxm[i] * sxm[j];
                else                 w = sxm[i] * sxm[j];
            }
            sw[p] = w;
        }

        // stage 26 sparse chunks: contiguous 2496B streams, read once
        #pragma unroll 8
        for (int t = tid; t < NS * CHUNKF4; t += 256) {
            int c = t / CHUNKF4;
            int w = t - c * CHUNKF4;
            sC[c * CHUNKF4_PAD + w] = WT4[(size_t)sgb[ND + c] + w];
        }
        __syncthreads();

        float acc = 0.0f;
        if (tid < NF) acc += fc_w[sfeat[tid]];   // linear term

        #pragma unroll 4
        for (int pass = 0; pass < CPASSES; ++pass) {
            int   p   = pass * 64 + slot;
            int   ij  = spij[p];
            int   i   = ij & 0xff;
            int   j   = ij >> 8;
            float wgt = sw[p];

            // a = W[i][f_j] fragment, v = W[j][f_i] fragment
            float4 a = (j >= ND) ? sC[(j - ND) * CHUNKF4_PAD + (i << 2) + q]
                                 : WT4[(size_t)sgb[j] + (i << 2) + q];
            float4 v = (i >= ND) ? sC[(i - ND) * CHUNKF4_PAD + (j << 2) + q]
                                 : WT4[(size_t)sgb[i] + (j << 2) + q];

            acc += wgt * (a.x * v.x + a.y * v.y + a.z * v.z + a.w * v.w);
        }

        #pragma unroll
        for (int off = 32; off > 0; off >>= 1)
            acc += __shfl_down(acc, off, 64);
        if ((tid & 63) == 0) sred[tid >> 6] = acc;
        __syncthreads();

        if (tid == 0) {
            float z = sred[0] + sred[1] + sred[2] + sred[3] + bias[0];
            out[b] = 1.0f / (1.0f + expf(-z));
        }
    }
}

// ---- fallback: verified round-0 kernel (native W layout, 8 lanes/pair) ----
#define PASSES ((NPAIRS + 31) / 32)
__global__ __launch_bounds__(256) void ffm_kernel(
    const float* __restrict__ x, const float* __restrict__ W,
    const float* __restrict__ fc_w, const float* __restrict__ bias,
    const int* __restrict__ offsets, float* __restrict__ out, int B)
{
    __shared__ int            sf[NF];
    __shared__ float          sxm[NF];
    __shared__ unsigned short spij[NPAIRS];
    __shared__ float          sred[4];

    const int b   = blockIdx.x;
    const int tid = threadIdx.x;

    if (tid < NF) {
        float xv = x[(size_t)b * NF + tid];
        int idx  = (tid < ND) ? 0 : (int)floorf(xv);
        sf[tid]  = idx + offsets[tid];
        sxm[tid] = (tid < ND) ? xv : 1.0f;
    }
    for (int p = tid; p < NPAIRS; p += 256) {
        int i = 0, base = 0;
        while (p >= base + (NF - i)) { base += NF - i; ++i; }
        int j = i + (p - base);
        spij[p] = (unsigned short)(i | (j << 8));
    }
    __syncthreads();

    const int slot = tid >> 3;
    const int quad = (tid >> 2) & 1;
    const int qi   = tid & 3;

    float acc = 0.0f;
    if (tid < NF) acc += fc_w[sf[tid]];

    #pragma unroll 5
    for (int pass = 0; pass < PASSES; ++pass) {
        int p  = pass * 32 + slot;
        int pc = (p < NPAIRS) ? p : (NPAIRS - 1);
        int ij = spij[pc];
        int i  = ij & 0xff;
        int j  = ij >> 8;

        float w;
        if (i == j)          w = (i < NF - 1) ? sxm[i] * sxm[i] : 0.0f;
        else if (j < NF - 1) w = 2.0f * sxm[i] * sxm[j];
        else                 w = sxm[i] * sxm[j];
        if (p >= NPAIRS) w = 0.0f;

        int row  = quad ? j : i;
        int feat = quad ? sf[i] : sf[j];
        const float4* vp = (const float4*)(W + ((size_t)row * FEAT + feat) * KDIM);
        float4 v = vp[qi];

        float4 u;
        u.x = __shfl_xor(v.x, 4, 64);
        u.y = __shfl_xor(v.y, 4, 64);
        u.z = __shfl_xor(v.z, 4, 64);
        u.w = __shfl_xor(v.w, 4, 64);

        float d = v.x * u.x + v.y * u.y + v.z * u.z + v.w * u.w;
        acc += 0.5f * w * d;
    }

    #pragma unroll
    for (int off = 32; off > 0; off >>= 1)
        acc += __shfl_down(acc, off, 64);
    if ((tid & 63) == 0) sred[tid >> 6] = acc;
    __syncthreads();

    if (tid == 0) {
        float z = sred[0] + sred[1] + sred[2] + sred[3] + bias[0];
        out[b] = 1.0f / (1.0f + expf(-z));
    }
}

extern "C" void kernel_launch(void* const* d_in, const int* in_sizes, int n_in,
                              void* d_out, int out_size, void* d_ws, size_t ws_size,
                              hipStream_t stream) {
    const float* x       = (const float*)d_in[0];
    const float* W       = (const float*)d_in[1];
    const float* fc_w    = (const float*)d_in[2];
    const float* bias    = (const float*)d_in[3];
    const int*   offsets = (const int*)d_in[4];

    float* out = (float*)d_out;
    const int B = in_sizes[0] / NF;

    const size_t WT_BYTES  = (size_t)FEAT * NF * KDIM * sizeof(float); // ~649 MB
    const size_t WT_ALIGN  = (WT_BYTES + 255) & ~(size_t)255;
    const size_t BIT_BYTES = (size_t)BITWORDS * sizeof(unsigned);

    if (d_ws != nullptr && ws_size >= WT_ALIGN + BIT_BYTES) {
        float4*   WT4  = (float4*)d_ws;
        unsigned* bits = (unsigned*)((char*)d_ws + WT_ALIGN);

        ffm_clear_bits<<<(BITWORDS + 255) / 256, 256, 0, stream>>>(bits);
        ffm_mark_bits<<<(B * NS + 255) / 256, 256, 0, stream>>>(x, offsets, bits, B);

        const int tgrid = (FEAT + TFEAT - 1) / TFEAT;   // 13,001
        ffm_transpose<<<tgrid, TTHREADS, 0, stream>>>((const float4*)W, WT4, bits);

        int mgrid = (B < MAIN_BLOCKS) ? B : MAIN_BLOCKS;
        if (mgrid < 1) mgrid = 1;
        ffm_main<<<mgrid, 256, 0, stream>>>(x, (const float4*)WT4, fc_w, bias,
                                            offsets, out, B);
    } else {
        ffm_kernel<<<B, 256, 0, stream>>>(x, W, fc_w, bias, offsets, out, B);
    }
}